// Round 3
// baseline (1381.055 us; speedup 1.0000x reference)
//
#include <hip/hip_runtime.h>

#define REG_CONST 0.05f
#define NCLASS 10
#define DIM 128
#define TILE 32
#define NBLOCKS 1024
#define NTHREADS 256

// DPP move: returns x shuffled by CTRL (quad_perm / row_ror), all lanes active.
template <int CTRL>
__device__ __forceinline__ float dpp_mov(float x) {
  return __int_as_float(
      __builtin_amdgcn_update_dpp(0, __float_as_int(x), CTRL, 0xF, 0xF, true));
}

__global__ __launch_bounds__(NTHREADS, 4)
void svm_fused(const float* __restrict__ X, const int* __restrict__ y,
               const float* __restrict__ w, float* __restrict__ out,
               int ntiles, float inv_n) {
  // Tiny LDS: double-buffered coefs + reduction scratch. No X staging, no w tile.
  __shared__ float4 coefs[2][TILE * 3];  // 2 x 32 rows x 3 float4 = 3 KiB
  __shared__ float4 red[5 * 256];        // 20 KiB epilogue scratch
  __shared__ float  lred[4];

  const int t  = threadIdx.x;
  const int l  = t & 63;
  const int wv = t >> 6;

  // phase-1 identity: 16 lanes per row; lane o covers float4 cols o and o+16
  const int o  = t & 15;
  const int rq = t >> 4;          // row-in-pass (0..15)
  // phase-2 identity: lane owns float4-column d4 for 4 rows (groups of 8)
  const int d4 = t & 31;
  const int rg = t >> 5;          // 0..7

  const float4* X4 = (const float4*)X;
  const float4* W4 = (const float4*)w;

  float4 g[NCLASS];
  #pragma unroll
  for (int c = 0; c < NCLASS; ++c) g[c] = make_float4(0.f, 0.f, 0.f, 0.f);
  float loss_acc = 0.f;

  int prev_row0 = 0;
  int have = 0;
  int p = 0;

  for (int tix = blockIdx.x; tix < ntiles; tix += gridDim.x) {
    const int row0 = tix * TILE;

    // ---- phase 1: scores for tile tix (2 passes x 16 rows), coefs -> LDS ----
    #pragma unroll
    for (int pass = 0; pass < 2; ++pass) {
      const int rr  = (pass << 4) + rq;       // row in tile 0..31
      const int row = row0 + rr;
      const float4 xa = X4[(size_t)row * 32 + o];
      const float4 xc = X4[(size_t)row * 32 + o + 16];
      const int yv = y[row];

      float s[NCLASS];
      #pragma unroll
      for (int c = 0; c < NCLASS; ++c) {
        const float4 wa = W4[c * 32 + o];
        const float4 wc = W4[c * 32 + o + 16];
        float v = fmaf(xa.x, wa.x, fmaf(xa.y, wa.y,
                  fmaf(xa.z, wa.z, xa.w * wa.w)));
        v = fmaf(xc.x, wc.x, fmaf(xc.y, wc.y,
            fmaf(xc.z, wc.z, fmaf(xc.w, wc.w, v))));
        s[c] = v;
      }
      // 16-lane butterfly: xor1,xor2 quad_perm; xor4 ds_swizzle; xor8 row_ror:8
      #pragma unroll
      for (int c = 0; c < NCLASS; ++c) {
        s[c] += dpp_mov<0xB1>(s[c]);          // quad_perm [1,0,3,2] : xor 1
        s[c] += dpp_mov<0x4E>(s[c]);          // quad_perm [2,3,0,1] : xor 2
        s[c] += __shfl_xor(s[c], 4);          // xor 4
        s[c] += dpp_mov<0x128>(s[c]);         // row_ror:8           : xor 8
      }

      float sy = s[0];
      #pragma unroll
      for (int c = 1; c < NCLASS; ++c) sy = (c == yv) ? s[c] : sy;

      float cnt = 0.f, rl = 0.f;
      float cf[NCLASS];
      #pragma unroll
      for (int c = 0; c < NCLASS; ++c) {
        float mg = s[c] - sy + 1.0f;
        bool act = (mg > 0.f) && (c != yv);
        cf[c] = act ? -1.f : 0.f;
        cnt += act ? 1.f : 0.f;
        rl  += act ? mg : 0.f;
      }
      #pragma unroll
      for (int c = 0; c < NCLASS; ++c) cf[c] = (c == yv) ? cnt : cf[c];

      if (o == 0) {
        coefs[p][rr * 3 + 0] = make_float4(cf[0], cf[1], cf[2], cf[3]);
        coefs[p][rr * 3 + 1] = make_float4(cf[4], cf[5], cf[6], cf[7]);
        coefs[p][rr * 3 + 2] = make_float4(cf[8], cf[9], 0.f, 0.f);
        loss_acc += rl;
      }
    }

    // ---- phase 2 of previous tile: X re-read from global (L2-hot) ----
    if (have) {
      const float4* cb = coefs[p ^ 1];
      #pragma unroll
      for (int k = 0; k < 4; ++k) {
        const int r = (k << 3) + rg;
        const float4 x4 = X4[(size_t)(prev_row0 + r) * 32 + d4];
        const float4 c0 = cb[r * 3 + 0];
        const float4 c1 = cb[r * 3 + 1];
        const float4 c2 = cb[r * 3 + 2];
#define ACC4(cc, gi)                         \
        g[gi].x = fmaf(cc, x4.x, g[gi].x);   \
        g[gi].y = fmaf(cc, x4.y, g[gi].y);   \
        g[gi].z = fmaf(cc, x4.z, g[gi].z);   \
        g[gi].w = fmaf(cc, x4.w, g[gi].w);
        ACC4(c0.x, 0) ACC4(c0.y, 1) ACC4(c0.z, 2) ACC4(c0.w, 3)
        ACC4(c1.x, 4) ACC4(c1.y, 5) ACC4(c1.z, 6) ACC4(c1.w, 7)
        ACC4(c2.x, 8) ACC4(c2.y, 9)
#undef ACC4
      }
    }

    __syncthreads();   // publish coefs[p]; retire coefs[p^1] for overwrite
    prev_row0 = row0;
    have = 1;
    p ^= 1;
  }

  // ---- epilogue phase 2 for the final tile ----
  if (have) {
    const float4* cb = coefs[p ^ 1];
    #pragma unroll
    for (int k = 0; k < 4; ++k) {
      const int r = (k << 3) + rg;
      const float4 x4 = X4[(size_t)(prev_row0 + r) * 32 + d4];
      const float4 c0 = cb[r * 3 + 0];
      const float4 c1 = cb[r * 3 + 1];
      const float4 c2 = cb[r * 3 + 2];
#define ACC4(cc, gi)                         \
      g[gi].x = fmaf(cc, x4.x, g[gi].x);     \
      g[gi].y = fmaf(cc, x4.y, g[gi].y);     \
      g[gi].z = fmaf(cc, x4.z, g[gi].z);     \
      g[gi].w = fmaf(cc, x4.w, g[gi].w);
      ACC4(c0.x, 0) ACC4(c0.y, 1) ACC4(c0.z, 2) ACC4(c0.w, 3)
      ACC4(c1.x, 4) ACC4(c1.y, 5) ACC4(c1.z, 6) ACC4(c1.w, 7)
      ACC4(c2.x, 8) ACC4(c2.y, 9)
#undef ACC4
    }
  }

  // ---- loss reduction ----
  float contrib = loss_acc * inv_n;
  if (blockIdx.x == 0) {                   // block 0 adds the reg terms
    float rw = 0.f;
    for (int i = t; i < NCLASS * DIM; i += NTHREADS) rw = fmaf(w[i], w[i], rw);
    contrib = fmaf(0.5f * REG_CONST, rw, contrib);
  }
  #pragma unroll
  for (int off = 32; off; off >>= 1) contrib += __shfl_down(contrib, off);
  if (l == 0) lred[wv] = contrib;
  __syncthreads();
  if (t == 0) atomicAdd(out + NCLASS * DIM, lred[0] + lred[1] + lred[2] + lred[3]);

  // ---- grad reduction: 8-way over row-groups, then atomics ----
  #pragma unroll
  for (int chunk = 0; chunk < 2; ++chunk) {
    __syncthreads();
    #pragma unroll
    for (int k = 0; k < 5; ++k) red[k * 256 + t] = g[chunk * 5 + k];
    __syncthreads();
    if (t < 160) {
      int k = t >> 5, dd = t & 31;
      float sx = 0.f, syy = 0.f, sz = 0.f, sw = 0.f;
      #pragma unroll
      for (int r8 = 0; r8 < 8; ++r8) {
        float4 v = red[k * 256 + (r8 << 5) + dd];
        sx += v.x; syy += v.y; sz += v.z; sw += v.w;
      }
      int c = chunk * 5 + k;
      int base = c * DIM + (dd << 2);
      float ax = sx * inv_n, ay = syy * inv_n, az = sz * inv_n, aw = sw * inv_n;
      if (blockIdx.x == 0) {
        ax += REG_CONST * w[base + 0];
        ay += REG_CONST * w[base + 1];
        az += REG_CONST * w[base + 2];
        aw += REG_CONST * w[base + 3];
      }
      atomicAdd(out + base + 0, ax);
      atomicAdd(out + base + 1, ay);
      atomicAdd(out + base + 2, az);
      atomicAdd(out + base + 3, aw);
    }
  }
}

extern "C" void kernel_launch(void* const* d_in, const int* in_sizes, int n_in,
                              void* d_out, int out_size, void* d_ws, size_t ws_size,
                              hipStream_t stream) {
  const float* X = (const float*)d_in[0];
  const int*   y = (const int*)d_in[1];
  const float* w = (const float*)d_in[2];
  float* out = (float*)d_out;
  int N = in_sizes[1];                 // y element count = 1,000,000
  int ntiles = N / TILE;               // 31250 (N divisible by 32)
  float inv_n = 1.0f / (float)N;
  hipMemsetAsync(d_out, 0, (size_t)out_size * sizeof(float), stream);
  svm_fused<<<NBLOCKS, NTHREADS, 0, stream>>>(X, y, w, out, ntiles, inv_n);
}

// Round 4
// 794.823 us; speedup vs baseline: 1.7376x; 1.7376x over previous
//
#include <hip/hip_runtime.h>

#define REG_CONST 0.05f
#define NCLASS 10
#define DIM 128
#define TILE 32
#define NBLOCKS 1024
#define NTHREADS 256

// DPP move: returns x shuffled by CTRL (quad_perm / row_ror), all lanes active.
template <int CTRL>
__device__ __forceinline__ float dpp_mov(float x) {
  return __int_as_float(
      __builtin_amdgcn_update_dpp(0, __float_as_int(x), CTRL, 0xF, 0xF, true));
}

// launch_bounds(256,2): VGPR budget 256. (256,4) made the backend target 64
// VGPRs (8 waves/EU heuristic) -> ~180B/thread/tile spill traffic, 1.4 GB of
// scratch writes to HBM (round-3 counters). Do not lower this.
__global__ __launch_bounds__(NTHREADS, 2)
void svm_fused(const float* __restrict__ X, const int* __restrict__ y,
               const float* __restrict__ w, float* __restrict__ out,
               int ntiles, float inv_n) {
  // Tiny LDS: double-buffered coefs + reduction scratch. No X staging, no w tile.
  __shared__ float4 coefs[2][TILE * 3];  // 2 x 32 rows x 3 float4 = 3 KiB
  __shared__ float4 red[5 * 256];        // 20 KiB epilogue scratch
  __shared__ float  lred[4];

  const int t  = threadIdx.x;
  const int l  = t & 63;
  const int wv = t >> 6;

  // phase-1 identity: 16 lanes per row; lane o covers float4 cols o and o+16
  const int o  = t & 15;
  const int rq = t >> 4;          // row-in-pass (0..15)
  // phase-2 identity: lane owns float4-column d4 for 4 rows (groups of 8)
  const int d4 = t & 31;
  const int rg = t >> 5;          // 0..7

  const float4* X4 = (const float4*)X;
  const float4* W4 = (const float4*)w;

  float4 g[NCLASS];
  #pragma unroll
  for (int c = 0; c < NCLASS; ++c) g[c] = make_float4(0.f, 0.f, 0.f, 0.f);
  float loss_acc = 0.f;

  int prev_row0 = 0;
  int have = 0;
  int p = 0;

  for (int tix = blockIdx.x; tix < ntiles; tix += gridDim.x) {
    const int row0 = tix * TILE;

    // ---- phase 1: scores for tile tix (2 passes x 16 rows), coefs -> LDS ----
    #pragma unroll
    for (int pass = 0; pass < 2; ++pass) {
      const int rr  = (pass << 4) + rq;       // row in tile 0..31
      const int row = row0 + rr;
      const float4 xa = X4[(size_t)row * 32 + o];
      const float4 xc = X4[(size_t)row * 32 + o + 16];
      const int yv = y[row];

      float s[NCLASS];
      #pragma unroll
      for (int c = 0; c < NCLASS; ++c) {
        const float4 wa = W4[c * 32 + o];
        const float4 wc = W4[c * 32 + o + 16];
        float v = fmaf(xa.x, wa.x, fmaf(xa.y, wa.y,
                  fmaf(xa.z, wa.z, xa.w * wa.w)));
        v = fmaf(xc.x, wc.x, fmaf(xc.y, wc.y,
            fmaf(xc.z, wc.z, fmaf(xc.w, wc.w, v))));
        s[c] = v;
      }
      // 16-lane butterfly: xor1,xor2 quad_perm; xor4 ds_swizzle; xor8 row_ror:8
      #pragma unroll
      for (int c = 0; c < NCLASS; ++c) {
        s[c] += dpp_mov<0xB1>(s[c]);          // quad_perm [1,0,3,2] : xor 1
        s[c] += dpp_mov<0x4E>(s[c]);          // quad_perm [2,3,0,1] : xor 2
        s[c] += __shfl_xor(s[c], 4);          // xor 4
        s[c] += dpp_mov<0x128>(s[c]);         // row_ror:8           : xor 8
      }

      float sy = s[0];
      #pragma unroll
      for (int c = 1; c < NCLASS; ++c) sy = (c == yv) ? s[c] : sy;

      float cnt = 0.f, rl = 0.f;
      float cf[NCLASS];
      #pragma unroll
      for (int c = 0; c < NCLASS; ++c) {
        float mg = s[c] - sy + 1.0f;
        bool act = (mg > 0.f) && (c != yv);
        cf[c] = act ? -1.f : 0.f;
        cnt += act ? 1.f : 0.f;
        rl  += act ? mg : 0.f;
      }
      #pragma unroll
      for (int c = 0; c < NCLASS; ++c) cf[c] = (c == yv) ? cnt : cf[c];

      if (o == 0) {
        coefs[p][rr * 3 + 0] = make_float4(cf[0], cf[1], cf[2], cf[3]);
        coefs[p][rr * 3 + 1] = make_float4(cf[4], cf[5], cf[6], cf[7]);
        coefs[p][rr * 3 + 2] = make_float4(cf[8], cf[9], 0.f, 0.f);
        loss_acc += rl;
      }
    }

    // ---- phase 2 of previous tile: X re-read from global (L2-hot) ----
    if (have) {
      const float4* cb = coefs[p ^ 1];
      #pragma unroll
      for (int k = 0; k < 4; ++k) {
        const int r = (k << 3) + rg;
        const float4 x4 = X4[(size_t)(prev_row0 + r) * 32 + d4];
        const float4 c0 = cb[r * 3 + 0];
        const float4 c1 = cb[r * 3 + 1];
        const float4 c2 = cb[r * 3 + 2];
#define ACC4(cc, gi)                         \
        g[gi].x = fmaf(cc, x4.x, g[gi].x);   \
        g[gi].y = fmaf(cc, x4.y, g[gi].y);   \
        g[gi].z = fmaf(cc, x4.z, g[gi].z);   \
        g[gi].w = fmaf(cc, x4.w, g[gi].w);
        ACC4(c0.x, 0) ACC4(c0.y, 1) ACC4(c0.z, 2) ACC4(c0.w, 3)
        ACC4(c1.x, 4) ACC4(c1.y, 5) ACC4(c1.z, 6) ACC4(c1.w, 7)
        ACC4(c2.x, 8) ACC4(c2.y, 9)
#undef ACC4
      }
    }

    __syncthreads();   // publish coefs[p]; retire coefs[p^1] for overwrite
    prev_row0 = row0;
    have = 1;
    p ^= 1;
  }

  // ---- epilogue phase 2 for the final tile ----
  if (have) {
    const float4* cb = coefs[p ^ 1];
    #pragma unroll
    for (int k = 0; k < 4; ++k) {
      const int r = (k << 3) + rg;
      const float4 x4 = X4[(size_t)(prev_row0 + r) * 32 + d4];
      const float4 c0 = cb[r * 3 + 0];
      const float4 c1 = cb[r * 3 + 1];
      const float4 c2 = cb[r * 3 + 2];
#define ACC4(cc, gi)                         \
      g[gi].x = fmaf(cc, x4.x, g[gi].x);     \
      g[gi].y = fmaf(cc, x4.y, g[gi].y);     \
      g[gi].z = fmaf(cc, x4.z, g[gi].z);     \
      g[gi].w = fmaf(cc, x4.w, g[gi].w);
      ACC4(c0.x, 0) ACC4(c0.y, 1) ACC4(c0.z, 2) ACC4(c0.w, 3)
      ACC4(c1.x, 4) ACC4(c1.y, 5) ACC4(c1.z, 6) ACC4(c1.w, 7)
      ACC4(c2.x, 8) ACC4(c2.y, 9)
#undef ACC4
    }
  }

  // ---- loss reduction ----
  float contrib = loss_acc * inv_n;
  if (blockIdx.x == 0) {                   // block 0 adds the reg terms
    float rw = 0.f;
    for (int i = t; i < NCLASS * DIM; i += NTHREADS) rw = fmaf(w[i], w[i], rw);
    contrib = fmaf(0.5f * REG_CONST, rw, contrib);
  }
  #pragma unroll
  for (int off = 32; off; off >>= 1) contrib += __shfl_down(contrib, off);
  if (l == 0) lred[wv] = contrib;
  __syncthreads();
  if (t == 0) atomicAdd(out + NCLASS * DIM, lred[0] + lred[1] + lred[2] + lred[3]);

  // ---- grad reduction: 8-way over row-groups, then atomics ----
  #pragma unroll
  for (int chunk = 0; chunk < 2; ++chunk) {
    __syncthreads();
    #pragma unroll
    for (int k = 0; k < 5; ++k) red[k * 256 + t] = g[chunk * 5 + k];
    __syncthreads();
    if (t < 160) {
      int k = t >> 5, dd = t & 31;
      float sx = 0.f, syy = 0.f, sz = 0.f, sw = 0.f;
      #pragma unroll
      for (int r8 = 0; r8 < 8; ++r8) {
        float4 v = red[k * 256 + (r8 << 5) + dd];
        sx += v.x; syy += v.y; sz += v.z; sw += v.w;
      }
      int c = chunk * 5 + k;
      int base = c * DIM + (dd << 2);
      float ax = sx * inv_n, ay = syy * inv_n, az = sz * inv_n, aw = sw * inv_n;
      if (blockIdx.x == 0) {
        ax += REG_CONST * w[base + 0];
        ay += REG_CONST * w[base + 1];
        az += REG_CONST * w[base + 2];
        aw += REG_CONST * w[base + 3];
      }
      atomicAdd(out + base + 0, ax);
      atomicAdd(out + base + 1, ay);
      atomicAdd(out + base + 2, az);
      atomicAdd(out + base + 3, aw);
    }
  }
}

extern "C" void kernel_launch(void* const* d_in, const int* in_sizes, int n_in,
                              void* d_out, int out_size, void* d_ws, size_t ws_size,
                              hipStream_t stream) {
  const float* X = (const float*)d_in[0];
  const int*   y = (const int*)d_in[1];
  const float* w = (const float*)d_in[2];
  float* out = (float*)d_out;
  int N = in_sizes[1];                 // y element count = 1,000,000
  int ntiles = N / TILE;               // 31250 (N divisible by 32)
  float inv_n = 1.0f / (float)N;
  hipMemsetAsync(d_out, 0, (size_t)out_size * sizeof(float), stream);
  svm_fused<<<NBLOCKS, NTHREADS, 0, stream>>>(X, y, w, out, ntiles, inv_n);
}

// Round 5
// 761.325 us; speedup vs baseline: 1.8140x; 1.0440x over previous
//
#include <hip/hip_runtime.h>

#define REG_CONST 0.05f
#define NCLASS 10
#define DIM 128
#define RSTEP 16          // rows per block-step (16 lanes per row x 16 rows = 256 thr)
#define NBLOCKS 512
#define NTHREADS 256

// DPP move: returns x shuffled by CTRL (quad_perm / row_ror), all lanes active.
template <int CTRL>
__device__ __forceinline__ float dpp_mov(float x) {
  return __int_as_float(
      __builtin_amdgcn_update_dpp(0, __float_as_int(x), CTRL, 0xF, 0xF, true));
}

// launch_bounds(256,2): VGPR budget 256. (256,4) made the backend target 64
// VGPRs -> 1.4 GB scratch spill traffic (round-3 counters). Do not lower.
__global__ __launch_bounds__(NTHREADS, 2)
void svm_fused(const float* __restrict__ X, const int* __restrict__ y,
               const float* __restrict__ w, float* __restrict__ out,
               int nsteps, float inv_n) {
  // LDS only used in the epilogue. Main loop: no LDS, no barriers.
  __shared__ float4 red[1280];    // 20 KiB: 4 waves x 16 o x 20 float4
  __shared__ float  lred[4];

  const int t  = threadIdx.x;
  const int l  = t & 63;
  const int wv = t >> 6;
  const int o  = t & 15;        // owns float4 columns o and o+16
  const int rq = t >> 4;        // row within the 16-row step

  const float4* X4 = (const float4*)X;
  const float4* W4 = (const float4*)w;

  float4 g[NCLASS][2];
  #pragma unroll
  for (int c = 0; c < NCLASS; ++c) {
    g[c][0] = make_float4(0.f, 0.f, 0.f, 0.f);
    g[c][1] = make_float4(0.f, 0.f, 0.f, 0.f);
  }
  float loss_acc = 0.f;

  // prologue: load step blockIdx.x
  int row = blockIdx.x * RSTEP + rq;
  float4 xa = X4[(size_t)row * 32 + o];
  float4 xc = X4[(size_t)row * 32 + o + 16];
  int yv = y[row];
  const int stride_rows = gridDim.x * RSTEP;

  for (int s = blockIdx.x; s < nsteps; s += gridDim.x) {
    // ---- depth-1 prefetch of next step (latency hidden under this step) ----
    const int rown = row + stride_rows;
    const int pr   = ((s + gridDim.x) < nsteps) ? rown : rq;  // clamp: safe row
    const float4 xan = X4[(size_t)pr * 32 + o];
    const float4 xcn = X4[(size_t)pr * 32 + o + 16];
    const int    yvn = y[pr];

    // ---- scores: 10 dots over this lane's 8 columns, w loop-invariant ----
    float sc[NCLASS];
    #pragma unroll
    for (int c = 0; c < NCLASS; ++c) {
      const float4 wa = W4[c * 32 + o];
      const float4 wc = W4[c * 32 + o + 16];
      float v = fmaf(xa.x, wa.x, fmaf(xa.y, wa.y,
                fmaf(xa.z, wa.z, xa.w * wa.w)));
      v = fmaf(xc.x, wc.x, fmaf(xc.y, wc.y,
          fmaf(xc.z, wc.z, fmaf(xc.w, wc.w, v))));
      sc[c] = v;
    }
    // 16-lane sum, all in VALU/DPP (no LDS): quad xor1, xor2, then ror4+ror8
    #pragma unroll
    for (int c = 0; c < NCLASS; ++c) {
      sc[c] += dpp_mov<0xB1>(sc[c]);    // quad_perm [1,0,3,2] : xor 1
      sc[c] += dpp_mov<0x4E>(sc[c]);    // quad_perm [2,3,0,1] : xor 2
      sc[c] += dpp_mov<0x124>(sc[c]);   // row_ror:4 (quad-sum rotation)
      sc[c] += dpp_mov<0x128>(sc[c]);   // row_ror:8
    }

    const float sy0 = sc[0];
    float sy = sy0;
    #pragma unroll
    for (int c = 1; c < NCLASS; ++c) sy = (c == yv) ? sc[c] : sy;

    float cnt = 0.f, rl = 0.f;
    float cf[NCLASS];
    #pragma unroll
    for (int c = 0; c < NCLASS; ++c) {
      const float mg = sc[c] - sy + 1.0f;
      const bool act = (mg > 0.f) && (c != yv);
      cf[c] = act ? -1.f : 0.f;
      cnt += act ? 1.f : 0.f;
      rl  += act ? mg : 0.f;
    }
    #pragma unroll
    for (int c = 0; c < NCLASS; ++c) cf[c] = (c == yv) ? cnt : cf[c];
    if (o == 0) loss_acc += rl;         // one lane per row group counts loss

    // ---- gradient: this lane's own columns, X already in registers ----
    #pragma unroll
    for (int c = 0; c < NCLASS; ++c) {
      g[c][0].x = fmaf(cf[c], xa.x, g[c][0].x);
      g[c][0].y = fmaf(cf[c], xa.y, g[c][0].y);
      g[c][0].z = fmaf(cf[c], xa.z, g[c][0].z);
      g[c][0].w = fmaf(cf[c], xa.w, g[c][0].w);
      g[c][1].x = fmaf(cf[c], xc.x, g[c][1].x);
      g[c][1].y = fmaf(cf[c], xc.y, g[c][1].y);
      g[c][1].z = fmaf(cf[c], xc.z, g[c][1].z);
      g[c][1].w = fmaf(cf[c], xc.w, g[c][1].w);
    }

    xa = xan; xc = xcn; yv = yvn; row = rown;
  }

  // ---- epilogue: reduce g across the 16 lanes sharing o (xor 16, 32) ----
  #pragma unroll
  for (int c = 0; c < NCLASS; ++c) {
    #pragma unroll
    for (int h = 0; h < 2; ++h) {
      float4 v = g[c][h];
      v.x += __shfl_xor(v.x, 16); v.y += __shfl_xor(v.y, 16);
      v.z += __shfl_xor(v.z, 16); v.w += __shfl_xor(v.w, 16);
      v.x += __shfl_xor(v.x, 32); v.y += __shfl_xor(v.y, 32);
      v.z += __shfl_xor(v.z, 32); v.w += __shfl_xor(v.w, 32);
      g[c][h] = v;
    }
  }
  if (l < 16) {
    #pragma unroll
    for (int c = 0; c < NCLASS; ++c) {
      red[wv * 320 + l * 20 + c * 2 + 0] = g[c][0];
      red[wv * 320 + l * 20 + c * 2 + 1] = g[c][1];
    }
  }
  __syncthreads();

  // ---- loss reduction ----
  float contrib = loss_acc * inv_n;
  if (blockIdx.x == 0) {                   // block 0 adds the reg terms
    float rw = 0.f;
    for (int i = t; i < NCLASS * DIM; i += NTHREADS) rw = fmaf(w[i], w[i], rw);
    contrib = fmaf(0.5f * REG_CONST, rw, contrib);
  }
  #pragma unroll
  for (int off = 32; off; off >>= 1) contrib += __shfl_down(contrib, off);
  if (l == 0) lred[wv] = contrib;
  __syncthreads();
  if (t == 0) atomicAdd(out + NCLASS * DIM, lred[0] + lred[1] + lred[2] + lred[3]);

  // ---- cross-wave grad reduce + atomics (320 float4 outputs) ----
  for (int idx = t; idx < 320; idx += NTHREADS) {
    const float4 a = red[idx];
    const float4 b = red[320 + idx];
    const float4 cc = red[640 + idx];
    const float4 d = red[960 + idx];
    float sx = a.x + b.x + cc.x + d.x;
    float sy2 = a.y + b.y + cc.y + d.y;
    float sz = a.z + b.z + cc.z + d.z;
    float sw = a.w + b.w + cc.w + d.w;
    const int oo = idx / 20;
    const int k  = idx % 20;
    const int c  = k >> 1;
    const int h  = k & 1;
    const int base = c * DIM + (oo + 16 * h) * 4;
    float ax = sx * inv_n, ay = sy2 * inv_n, az = sz * inv_n, aw = sw * inv_n;
    if (blockIdx.x == 0) {
      ax += REG_CONST * w[base + 0];
      ay += REG_CONST * w[base + 1];
      az += REG_CONST * w[base + 2];
      aw += REG_CONST * w[base + 3];
    }
    atomicAdd(out + base + 0, ax);
    atomicAdd(out + base + 1, ay);
    atomicAdd(out + base + 2, az);
    atomicAdd(out + base + 3, aw);
  }
}

extern "C" void kernel_launch(void* const* d_in, const int* in_sizes, int n_in,
                              void* d_out, int out_size, void* d_ws, size_t ws_size,
                              hipStream_t stream) {
  const float* X = (const float*)d_in[0];
  const int*   y = (const int*)d_in[1];
  const float* w = (const float*)d_in[2];
  float* out = (float*)d_out;
  int N = in_sizes[1];                 // y element count = 1,000,000
  int nsteps = N / RSTEP;              // 62500 (N divisible by 16)
  float inv_n = 1.0f / (float)N;
  hipMemsetAsync(d_out, 0, (size_t)out_size * sizeof(float), stream);
  svm_fused<<<NBLOCKS, NTHREADS, 0, stream>>>(X, y, w, out, nsteps, inv_n);
}